// Round 1
// baseline (188.120 us; speedup 1.0000x reference)
//
#include <hip/hip_runtime.h>
#include <hip/hip_bf16.h>

#define IN_CNT 64
#define FEAT   1024
#define BATCH  256

#define BM 256
#define BN 256
#define BK 64
#define KT (FEAT / BK)   // 16 K-tiles

typedef __attribute__((ext_vector_type(4))) float f32x4;
typedef __attribute__((ext_vector_type(8))) short short8;   // 8 bf16 = one MFMA A/B frag

__device__ __forceinline__ short f2bf(float f) {
    __hip_bfloat16 h = __float2bfloat16(f);   // RNE; compiler pairs into v_cvt_pk_bf16_f32
    return __builtin_bit_cast(short, h);
}

__device__ __forceinline__ short8 pack8(f32x4 a, f32x4 b) {
    short8 v;
    v[0] = f2bf(a[0]); v[1] = f2bf(a[1]); v[2] = f2bf(a[2]); v[3] = f2bf(a[3]);
    v[4] = f2bf(b[0]); v[5] = f2bf(b[1]); v[6] = f2bf(b[2]); v[7] = f2bf(b[3]);
    return v;
}

// One block = one 256x256 output tile of one of the 64 GEMMs.
// grid = 64 * (1024/256) = 256 blocks, 512 threads (8 waves, 2Mx4N wave grid).
__global__ __launch_bounds__(512, 2)
void split_linear_kernel(const float* __restrict__ x,
                         const float* __restrict__ W,
                         float* __restrict__ out)
{
    // double-buffered LDS: per buffer A[256][64] bf16 (16384 shorts) then B[256][64]
    __shared__ short lds[2][2 * BM * BK];

    const int tid  = threadIdx.x;
    const int gi   = blockIdx.x >> 2;            // which linear (0..63)
    const int ncol = (blockIdx.x & 3) << 8;      // N-tile offset: 0/256/512/768

    // ---- staging coords: thread covers 8 floats (2 float4) per row, 4 row-passes
    const int srow = tid >> 3;                   // 0..63
    const int sc8  = tid & 7;                    // which 8-float chunk in the 64-wide K slab
    const float* Abase = x + (size_t)gi * FEAT + (size_t)sc8 * 8;                   // + b*65536 + kt*64
    const float* Bbase = W + ((size_t)gi * FEAT + (size_t)ncol) * FEAT + (size_t)sc8 * 8; // + o*1024 + kt*64

    // ---- wave/frag coords
    const int lane = tid & 63;
    const int wid  = tid >> 6;
    const int wm   = wid >> 2;                   // 0..1  (M wave)
    const int wn   = wid & 3;                    // 0..3  (N wave)
    const int lr   = lane & 15;
    const int lh   = lane >> 4;
    const int sw   = (lr & 7) << 3;              // XOR swizzle (in shorts): (row&7)*8

    f32x4 ra[4][2], rb[4][2];
    f32x4 acc[8][4];
#pragma unroll
    for (int m = 0; m < 8; ++m)
#pragma unroll
        for (int n = 0; n < 4; ++n)
            acc[m][n] = (f32x4){0.f, 0.f, 0.f, 0.f};

    auto LOADT = [&](int kt) {
#pragma unroll
        for (int p = 0; p < 4; ++p) {
            const int r = srow + p * 64;
            const float* qa = Abase + (size_t)r * (IN_CNT * FEAT) + (size_t)kt * BK;
            ra[p][0] = *(const f32x4*)qa;
            ra[p][1] = *(const f32x4*)(qa + 4);
            const float* qb = Bbase + (size_t)r * FEAT + (size_t)kt * BK;
            rb[p][0] = *(const f32x4*)qb;
            rb[p][1] = *(const f32x4*)(qb + 4);
        }
    };

    auto WRITET = [&](int buf) {
#pragma unroll
        for (int p = 0; p < 4; ++p) {
            const int r  = srow + p * 64;
            const int cs = (sc8 << 3) ^ ((r & 7) << 3);   // swizzled short offset in row
            *(short8*)&lds[buf][(r << 6) + cs]               = pack8(ra[p][0], ra[p][1]);
            *(short8*)&lds[buf][BM * BK + (r << 6) + cs]     = pack8(rb[p][0], rb[p][1]);
        }
    };

    auto COMPUTE = [&](int buf) {
#pragma unroll
        for (int ks = 0; ks < 2; ++ks) {
            const int kc = (((ks << 5) + (lh << 3)) ^ sw);  // swizzled k-offset (shorts)
            short8 bfr[4];
#pragma unroll
            for (int nf = 0; nf < 4; ++nf)
                bfr[nf] = *(const short8*)&lds[buf][BM * BK + (((wn << 6) + (nf << 4) + lr) << 6) + kc];
#pragma unroll
            for (int mf = 0; mf < 8; ++mf) {
                short8 af = *(const short8*)&lds[buf][(((wm << 7) + (mf << 4) + lr) << 6) + kc];
#pragma unroll
                for (int nf = 0; nf < 4; ++nf)
                    acc[mf][nf] = __builtin_amdgcn_mfma_f32_16x16x32_bf16(
                        af, bfr[nf], acc[mf][nf], 0, 0, 0);
            }
        }
    };

    // ---- prologue
    LOADT(0);
    WRITET(0);
    LOADT(1);
    __syncthreads();

    // ---- main loop: write staged regs -> issue next loads -> compute -> barrier
#pragma unroll 2
    for (int kt = 0; kt < KT; ++kt) {
        if (kt + 1 < KT) {
            WRITET((kt + 1) & 1);
            if (kt + 2 < KT) LOADT(kt + 2);
        }
        COMPUTE(kt & 1);
        __syncthreads();
    }

    // ---- epilogue: C/D layout col=lane&15, row=(lane>>4)*4+reg  [m89-verified]
    const int m0 = (wm << 7) + (lh << 2);
    const int n0 = ncol + (wn << 6) + lr;
#pragma unroll
    for (int mf = 0; mf < 8; ++mf) {
#pragma unroll
        for (int nf = 0; nf < 4; ++nf) {
            const f32x4 v = acc[mf][nf];
            const int m = m0 + (mf << 4);
            const int n = n0 + (nf << 4);
#pragma unroll
            for (int j = 0; j < 4; ++j)
                out[((size_t)(m + j) * IN_CNT + gi) * FEAT + n] = v[j];
        }
    }
}

extern "C" void kernel_launch(void* const* d_in, const int* in_sizes, int n_in,
                              void* d_out, int out_size, void* d_ws, size_t ws_size,
                              hipStream_t stream) {
    const float* x   = (const float*)d_in[0];
    const float* W   = (const float*)d_in[1];
    float*       out = (float*)d_out;

    dim3 grid(IN_CNT * (FEAT / BN));   // 256 blocks: one 256x256 tile each
    dim3 block(512);
    hipLaunchKernelGGL(split_linear_kernel, grid, block, 0, stream, x, W, out);
}

// Round 2
// 93.229 us; speedup vs baseline: 2.0178x; 2.0178x over previous
//
#include <hip/hip_runtime.h>
#include <hip/hip_bf16.h>

#define IN_CNT 64
#define FEAT   1024
#define BATCH  256

#define BM 256
#define BN 256
#define BK 32
#define KT (FEAT / BK)   // 32 K-tiles

typedef __attribute__((ext_vector_type(4))) float f32x4;
typedef __attribute__((ext_vector_type(8))) short short8;   // 8 bf16 = one MFMA A/B frag

__device__ __forceinline__ short f2bf(float f) {
    __hip_bfloat16 h = __float2bfloat16(f);
    return __builtin_bit_cast(short, h);
}

__device__ __forceinline__ short8 pack8(f32x4 a, f32x4 b) {
    short8 v;
    v[0] = f2bf(a[0]); v[1] = f2bf(a[1]); v[2] = f2bf(a[2]); v[3] = f2bf(a[3]);
    v[4] = f2bf(b[0]); v[5] = f2bf(b[1]); v[6] = f2bf(b[2]); v[7] = f2bf(b[3]);
    return v;
}

// Relaxed workgroup barrier: drains LDS ops (cross-wave visibility) but NOT
// vmcnt -> prefetch global loads stay in flight across the barrier (T4).
__device__ __forceinline__ void barrier_nodrain() {
    asm volatile("s_waitcnt lgkmcnt(0)" ::: "memory");
    __builtin_amdgcn_s_barrier();
    asm volatile("" ::: "memory");
}

// swizzle slot function: row -> 2-bit xor for the 4x16B slots of a 64B row.
// Chosen so the 16 rows of a frag-read spread over 8 banks (2-way = free).
__device__ __forceinline__ int SWZ(int r) { return (r + (r >> 2)) & 3; }

__global__ __launch_bounds__(512, 2)
void split_linear_kernel(const float* __restrict__ x,
                         const float* __restrict__ W,
                         float* __restrict__ out)
{
    // main loop: 2 bufs x (A 8192 + B 8192 shorts) = 64 KB.
    // epilogue reuses it as float[64][256] (64 KB) stripe-transpose scratch.
    __shared__ __align__(16) short lds[2 * 2 * BM * BK];

    const int tid = threadIdx.x;

    // bijective XCD swizzle (256 % 8 == 0): logical ids 4k..4k+3 (same gi)
    // land on one XCD -> x tile L2-shared among the 4 N-blocks.
    const int bid = blockIdx.x;
    const int swz = ((bid & 7) << 5) | (bid >> 3);
    const int gi   = swz >> 2;            // 0..63
    const int ncol = (swz & 3) << 8;      // 0/256/512/768

    // ---- staging coords: thread covers 16 consecutive floats of one row
    const int r   = tid >> 1;             // row 0..255 (A: b, B: o)
    const int h   = tid & 1;              // which 16-float half of the 32-wide K slab
    const int swr = SWZ(r);
    const int sl0 = ((2 * h) ^ swr) << 3;       // short offsets of the 2 write slots
    const int sl1 = ((2 * h + 1) ^ swr) << 3;

    const float* Abase = x + ((size_t)r * IN_CNT + gi) * FEAT + h * 16;
    const float* Bbase = W + ((size_t)gi * FEAT + ncol + r) * FEAT + h * 16;

    // ---- wave/frag coords
    const int lane = tid & 63;
    const int wid  = tid >> 6;
    const int wm   = wid >> 2;            // 0..1
    const int wn   = wid & 3;             // 0..3
    const int lr   = lane & 15;
    const int lh   = lane >> 4;
    const int slr  = (lh ^ SWZ(lr)) << 3; // frag read slot offset (shorts)

    f32x4 sA[2][4], sB[2][4];             // two staging sets (set = tile & 1)
    f32x4 acc[8][4];
#pragma unroll
    for (int m = 0; m < 8; ++m)
#pragma unroll
        for (int n = 0; n < 4; ++n)
            acc[m][n] = (f32x4){0.f, 0.f, 0.f, 0.f};

    auto LOADT = [&](int kt, int s) {
        const float* qa = Abase + kt * BK;
        const float* qb = Bbase + kt * BK;
#pragma unroll
        for (int i = 0; i < 4; ++i) {
            sA[s][i] = *(const f32x4*)(qa + i * 4);
            sB[s][i] = *(const f32x4*)(qb + i * 4);
        }
    };

    auto WRITET = [&](int s, int b) {
        short* dst = lds + b * 16384 + r * 32;
        *(short8*)(dst + sl0)        = pack8(sA[s][0], sA[s][1]);
        *(short8*)(dst + sl1)        = pack8(sA[s][2], sA[s][3]);
        *(short8*)(dst + 8192 + sl0) = pack8(sB[s][0], sB[s][1]);
        *(short8*)(dst + 8192 + sl1) = pack8(sB[s][2], sB[s][3]);
    };

    auto COMPUTE = [&](int b) {
        const short* base = lds + b * 16384;
        short8 bf[4];
#pragma unroll
        for (int nf = 0; nf < 4; ++nf)
            bf[nf] = *(const short8*)(base + 8192 + (wn * 64 + nf * 16 + lr) * 32 + slr);
#pragma unroll
        for (int mf = 0; mf < 8; ++mf) {
            short8 af = *(const short8*)(base + (wm * 128 + mf * 16 + lr) * 32 + slr);
#pragma unroll
            for (int nf = 0; nf < 4; ++nf)
                acc[mf][nf] = __builtin_amdgcn_mfma_f32_16x16x32_bf16(
                    af, bf[nf], acc[mf][nf], 0, 0, 0);
        }
    };

    // ---- prologue: tiles 0,1 loaded; tile 0 staged; tile 2 in flight
    LOADT(0, 0);
    LOADT(1, 1);
    WRITET(0, 0);
    LOADT(2, 0);
    barrier_nodrain();

    // ---- main loop, 2 iterations per trip so set/buf indices are literal
    for (int kt = 0; kt < KT; kt += 2) {
        // even step: compute tile kt (buf0); stage tile kt+1; load tile kt+3
        WRITET(1, 1);
        if (kt + 3 < KT) LOADT(kt + 3, 1);
        COMPUTE(0);
        barrier_nodrain();
        // odd step: compute tile kt+1 (buf1); stage tile kt+2; load tile kt+4
        if (kt + 2 < KT) WRITET(0, 0);
        if (kt + 4 < KT) LOADT(kt + 4, 0);
        COMPUTE(1);
        barrier_nodrain();
    }

    // ---- epilogue: stripe-transpose through LDS -> 1KB-contiguous f32x4 stores
    // C/D frag layout: col = lane&15 (n), row = lh*4 + j (m)  [m89-verified]
    float* elds = (float*)lds;   // [64][256] f32 = 64 KB
#pragma unroll
    for (int s = 0; s < 4; ++s) {               // 4 stripes of 64 m-rows
        barrier_nodrain();                       // previous stripe fully read
        if (wm == (s >> 1)) {
            const int mfb = (s & 1) * 4;
#pragma unroll
            for (int f = 0; f < 4; ++f)
#pragma unroll
                for (int nf = 0; nf < 4; ++nf)
#pragma unroll
                    for (int j = 0; j < 4; ++j)
                        elds[(f * 16 + lh * 4 + j) * 256 + wn * 64 + nf * 16 + lr]
                            = acc[mfb + f][nf][j];
        }
        barrier_nodrain();
#pragma unroll
        for (int rr = 0; rr < 8; ++rr) {         // wave w stores rows w*8..w*8+7
            const int rowl = wid * 8 + rr;
            f32x4 v = *(const f32x4*)&elds[rowl * 256 + lane * 4];
            const int m = s * 64 + rowl;
            *(f32x4*)&out[((size_t)m * IN_CNT + gi) * FEAT + ncol + lane * 4] = v;
        }
    }
}

extern "C" void kernel_launch(void* const* d_in, const int* in_sizes, int n_in,
                              void* d_out, int out_size, void* d_ws, size_t ws_size,
                              hipStream_t stream) {
    const float* x   = (const float*)d_in[0];
    const float* W   = (const float*)d_in[1];
    float*       out = (float*)d_out;

    dim3 grid(IN_CNT * (FEAT / BN));   // 256 blocks: one 256x256 tile each
    dim3 block(512);
    hipLaunchKernelGGL(split_linear_kernel, grid, block, 0, stream, x, W, out);
}